// Round 4
// baseline (150.147 us; speedup 1.0000x reference)
//
#include <hip/hip_runtime.h>

constexpr int TPB   = 256;
constexpr int ITEMS = 32;
constexpr int TILE  = TPB * ITEMS;   // 8192 elements per block
constexpr int GRID  = 977;           // 977*8192 = 8,003,584 >= 8,000,000
constexpr unsigned MAGIC = 0xC0DE600Du;   // != 0xAAAAAAAA ws-poison, != 0

// native 4-float vector for __builtin_nontemporal_* (HIP float4 is a class
// type the builtin rejects; this is layout-identical).
typedef float fx4 __attribute__((ext_vector_type(4)));

// Clamp monoid: f(x) = min(max(x + A, B), C). compose(l, r) (l applied first):
//   A = Al + Ar;  B = max(Bl + Ar, Br);  C = min(max(Cl + Ar, Br), Cr)
// Affine monoid: f(x) = P*x + Q. compose(l, r): P = Pl*Pr; Q = Pr*Ql + Qr.
//
// R14 = R10's measured-best direct per-thread memory path (LDS staging from
// R12/R13 reverted: falsified — L1/L2 absorb the per-thread strided pattern;
// staging was pure overhead), plus strictly-local wins:
//  * k32 hoist: p == k^ITEMS for every full thread; phase-C loop no longer
//    carries `p *= k` (32 dependent v_mul per thread deleted, both paths).
//  * Non-temporal loads/stores on the streaming data (x read once, out
//    written once — keep them from thrashing L2/L3 retention).
//  * lane-0 exact fix-up shrunk 64 -> 32 elements: tid 1 is saturated on the
//    fast path (else fallback), so its only error is B-start damped by
//    k^32 <= 1.1e-5 (k<0.7) — validated by R12/R13 passing with identical
//    absmax. Speculative stores now cover tid >= 1.
// Structure otherwise identical to R10: gate-free throughput path, exact
// publishes, speculative epilogue, runtime fallback (exact R9 broadcast).
// Deadlock-freedom: waits target only lower blockIdx; ascending dispatch;
// 977 blocks at 4/CU fully co-resident.

#define AT_LOAD(p)    __hip_atomic_load((p), __ATOMIC_RELAXED, __HIP_MEMORY_SCOPE_AGENT)
#define AT_STORE(p,v) __hip_atomic_store((p), (v), __ATOMIC_RELAXED, __HIP_MEMORY_SCOPE_AGENT)

__global__ __launch_bounds__(TPB, 4)
void awbm_kernel(const float* __restrict__ x,
                 const float* __restrict__ pBFI,
                 const float* __restrict__ pK,
                 const float* __restrict__ pSmax,
                 float* __restrict__ out,
                 float* __restrict__ ws,
                 int T)
{
    __shared__ float sm3[12];    // phase-A wave aggregates (3 x 4 waves)
    __shared__ float sm2[8];     // phase-C wave aggregates (2 x 4 waves)
    __shared__ float bc[2];      // fallback broadcast: S / B at block start

    const int tid  = threadIdx.x;
    const int lane = tid & 63;
    const int wv   = tid >> 6;
    const int b    = blockIdx.x;
    const int gbase = b * TILE;
    const int toff  = tid * ITEMS;
    const bool full = (gbase + toff) < T;      // all-or-nothing (divisibility)

    // ---- stage x -> registers FIRST: 16 independent NT dwordx4 loads ----
    float d[ITEMS];
    if (full) {
        const fx4* x4 = (const fx4*)x + ((long)(gbase + toff) >> 1);
        fx4 v[16];
#pragma unroll
        for (int u = 0; u < 16; ++u) v[u] = __builtin_nontemporal_load(&x4[u]);
#pragma unroll
        for (int u = 0; u < 16; ++u) {
            d[2 * u]     = v[u].x - v[u].y;
            d[2 * u + 1] = v[u].z - v[u].w;
        }
    }

    float*    scrA = ws;
    float*    scrB = ws + GRID;
    float*    scrC = ws + 2 * GRID;
    float*    scrP = ws + 3 * GRID;
    float*    scrQ = ws + 4 * GRID;
    unsigned* f1   = (unsigned*)(ws + 5 * GRID);
    unsigned* f2   = (unsigned*)(ws + 6 * GRID);

    const float bfi  = pBFI[0];
    const float k    = pK[0];
    const float smax = pSmax[0];
    const float omb  = 1.0f - bfi;
    const float omk  = 1.0f - k;
    const float INF  = __builtin_inff();
    const float k2 = k * k, k4 = k2 * k2, k8 = k4 * k4, k16 = k8 * k8;
    const float k32 = k16 * k16;               // per-full-thread affine P

    // ---- Phase A: per-thread clamp fold (identity if empty) ----
    float rA = 0.f, rB = -INF, rC = INF;
    if (full) {
#pragma unroll
        for (int j = 0; j < ITEMS; ++j) {
            float dd = d[j];
            rA += dd;
            rB = fmaxf(rB + dd, 0.f);
            rC = fminf(fmaxf(rC + dd, 0.f), smax);
        }
    }
#pragma unroll
    for (int s = 1; s < 64; s <<= 1) {
        float pA = __shfl_up(rA, s, 64), pB = __shfl_up(rB, s, 64), pC = __shfl_up(rC, s, 64);
        if (lane >= s) {
            float nA = pA + rA, nB = fmaxf(pB + rA, rB), nC = fminf(fmaxf(pC + rA, rB), rC);
            rA = nA; rB = nB; rC = nC;
        }
    }
    if (lane == 63) { sm3[wv * 3] = rA; sm3[wv * 3 + 1] = rB; sm3[wv * 3 + 2] = rC; }
    __syncthreads();   // B1
    float wA = 0.f, wB = -INF, wC = INF;       // exclusive cross-wave prefix
    for (int i = 0; i < wv; ++i) {
        float a = sm3[i * 3], bb = sm3[i * 3 + 1], c = sm3[i * 3 + 2];
        float nA = wA + a, nB = fmaxf(wB + a, bb), nC = fminf(fmaxf(wC + a, bb), c);
        wA = nA; wB = nB; wC = nC;
    }
    {   // thread inclusive across block
        float nA = wA + rA, nB = fmaxf(wB + rA, rB), nC = fminf(fmaxf(wC + rA, rB), rC);
        rA = nA; rB = nB; rC = nC;
    }
    if (tid == TPB - 1) {                      // publish1: exact, gate-free
        AT_STORE(&scrA[b], rA); AT_STORE(&scrB[b], rB); AT_STORE(&scrC[b], rC);
        __atomic_signal_fence(__ATOMIC_SEQ_CST);
        __builtin_amdgcn_s_waitcnt(0);
        __atomic_signal_fence(__ATOMIC_SEQ_CST);
        AT_STORE(&f1[b], MAGIC);
    }
    float eA, eB, eC;                          // thread-exclusive prefix map
    {
        float pA = __shfl_up(rA, 1, 64), pB = __shfl_up(rB, 1, 64), pC = __shfl_up(rC, 1, 64);
        eA = (lane == 0) ? wA : pA;
        eB = (lane == 0) ? wB : pB;
        eC = (lane == 0) ? wC : pC;
    }

    // ---- fast/fallback decision (B2) ----
    int bad = (full && tid > 0 && eB < eC) ? 1 : 0;
    int cnt = __syncthreads_count(bad);
    const bool fallback = (cnt != 0) || !(k > 0.0f && k < 0.70f) || (T - gbase < 64);

    if (!fallback) {
        // ================= FAST PATH (gate-free throughput) =================
        float S = fminf(fmaxf(0.5f + eA, eB), eC);   // exact for saturated threads
        float c = 0.f;
        if (full) {
#pragma unroll
            for (int j = 0; j < ITEMS; ++j) {
                float dd = d[j];
                float S1 = fmaxf(S + dd, 0.f);
                float ex = fmaxf(S1 - smax, 0.f);
                S = S1 - ex;
                float w = c + bfi * ex;
                d[j] = omb * ex + omk * w;
                c = k * w;
            }
        }
        float p = full ? k32 : 1.f;            // hoisted: P = k^ITEMS, constant
#pragma unroll
        for (int s = 1; s < 64; s <<= 1) {
            float pp = __shfl_up(p, s, 64), pc = __shfl_up(c, s, 64);
            if (lane >= s) {
                float nq = p * pc + c;
                p = pp * p;
                c = nq;
            }
        }
        if (lane == 63) { sm2[wv * 2] = p; sm2[wv * 2 + 1] = c; }
        __syncthreads();   // B3
        float wP = 1.f, wQ = 0.f;
        for (int i = 0; i < wv; ++i) {
            float gp = sm2[i * 2], gq = sm2[i * 2 + 1];
            wQ = gp * wQ + gq;
            wP = wP * gp;
        }
        {
            float nq = p * wQ + c;
            p = wP * p;
            c = nq;
        }
        if (tid == TPB - 1) {                  // publish2: exact to <1e-35, gate-free
            AT_STORE(&scrP[b], p); AT_STORE(&scrQ[b], c);
            __atomic_signal_fence(__ATOMIC_SEQ_CST);
            __builtin_amdgcn_s_waitcnt(0);
            __atomic_signal_fence(__ATOMIC_SEQ_CST);
            AT_STORE(&f2[b], MAGIC);
        }
        float eP, eQ;
        {
            float pp = __shfl_up(p, 1, 64), pc = __shfl_up(c, 1, 64);
            eP = (lane == 0) ? wP : pp;
            eQ = (lane == 0) ? wQ : pc;
        }

        // speculative epilogue + NT store: threads >= 1, zero waits
        // (tid 1 saturated => S exact; B-start error damped by k^32 <= 1.1e-5)
        if (full && tid >= 1) {
            float Bst = eP * 1.0f + eQ;        // guess B_blockstart=1; err <= k^(32*tid)
            float f = omk * Bst;
#pragma unroll
            for (int j = 0; j < ITEMS; ++j) { d[j] += f; f *= k; }
            fx4* o4 = (fx4*)out + ((long)(gbase + toff) >> 2);
#pragma unroll
            for (int u = 0; u < 8; ++u) {
                fx4 v; v.x = d[4 * u]; v.y = d[4 * u + 1]; v.z = d[4 * u + 2]; v.w = d[4 * u + 3];
                __builtin_nontemporal_store(v, &o4[u]);
            }
        }

        // lane-0 fix-up: both 1-hop gates + exact serial recompute of [0,32)
        if (tid == 0) {
            float Sst;
            if (b == 0) Sst = 0.5f;
            else {
                float aA = 0.f, aB = -INF, aC = INF;
                int j = b - 1;
                for (;;) {
                    if (j < 0) { Sst = fminf(fmaxf(0.5f + aA, aB), aC); break; }
                    while (AT_LOAD(&f1[j]) != MAGIC) __builtin_amdgcn_s_sleep(1);
                    __atomic_signal_fence(__ATOMIC_ACQUIRE);
                    float Aj = AT_LOAD(&scrA[j]), Bj = AT_LOAD(&scrB[j]), Cj = AT_LOAD(&scrC[j]);
                    float nA = Aj + aA, nB = fmaxf(Bj + aA, aB), nC = fminf(fmaxf(Cj + aA, aB), aC);
                    aA = nA; aB = nB; aC = nC;
                    if (aB >= aC) { Sst = aC; break; }
                    --j;
                }
            }
            float Bcur;
            if (b == 0) Bcur = 1.0f;
            else {
                float accP = 1.f, Bacc = 0.f;
                int j = b - 1;
                for (;;) {
                    if (j < 0) { Bacc += accP * 1.0f; break; }
                    if (accP < 1e-35f) break;
                    while (AT_LOAD(&f2[j]) != MAGIC) __builtin_amdgcn_s_sleep(1);
                    __atomic_signal_fence(__ATOMIC_ACQUIRE);
                    float Pj = AT_LOAD(&scrP[j]), Qj = AT_LOAD(&scrQ[j]);
                    Bacc += accP * Qj;
                    accP *= Pj;
                    --j;
                }
                Bcur = Bacc;
            }
            // exact recompute of elements [gbase, gbase+32)
            const fx4* xf = (const fx4*)x + ((long)gbase >> 1);
            fx4 vv[16];
#pragma unroll
            for (int u = 0; u < 16; ++u) vv[u] = xf[u];
            float Sc = Sst;
            float o[32];
#pragma unroll
            for (int j = 0; j < 32; ++j) {
                float dd = (j & 1) ? (vv[j >> 1].z - vv[j >> 1].w)
                                   : (vv[j >> 1].x - vv[j >> 1].y);
                float S1 = fmaxf(Sc + dd, 0.f);
                float ex = fmaxf(S1 - smax, 0.f);
                Sc = S1 - ex;
                Bcur += bfi * ex;
                float bf = omk * Bcur;
                Bcur -= bf;
                o[j] = omb * ex + bf;
            }
            fx4* o4 = (fx4*)out + ((long)gbase >> 2);
#pragma unroll
            for (int u = 0; u < 8; ++u) {
                fx4 v; v.x = o[4 * u]; v.y = o[4 * u + 1]; v.z = o[4 * u + 2]; v.w = o[4 * u + 3];
                __builtin_nontemporal_store(v, &o4[u]);
            }
        }
    } else {
        // ================= FALLBACK (exact R9 path) =================
        if (tid == 0) {
            float aA = 0.f, aB = -INF, aC = INF;
            float Sst;
            int j = b - 1;
            for (;;) {
                if (j < 0) { Sst = fminf(fmaxf(0.5f + aA, aB), aC); break; }
                while (AT_LOAD(&f1[j]) != MAGIC) __builtin_amdgcn_s_sleep(1);
                __atomic_signal_fence(__ATOMIC_ACQUIRE);
                float Aj = AT_LOAD(&scrA[j]), Bj = AT_LOAD(&scrB[j]), Cj = AT_LOAD(&scrC[j]);
                float nA = Aj + aA, nB = fmaxf(Bj + aA, aB), nC = fminf(fmaxf(Cj + aA, aB), aC);
                aA = nA; aB = nB; aC = nC;
                if (aB >= aC) { Sst = aC; break; }
                --j;
            }
            bc[0] = Sst;
        }
        __syncthreads();
        float S = fminf(fmaxf(bc[0] + eA, eB), eC);
        float c = 0.f;
        if (full) {
#pragma unroll
            for (int j = 0; j < ITEMS; ++j) {
                float dd = d[j];
                float S1 = fmaxf(S + dd, 0.f);
                float ex = fmaxf(S1 - smax, 0.f);
                S = S1 - ex;
                float w = c + bfi * ex;
                d[j] = omb * ex + omk * w;
                c = k * w;
            }
        }
        float p = full ? k32 : 1.f;
#pragma unroll
        for (int s = 1; s < 64; s <<= 1) {
            float pp = __shfl_up(p, s, 64), pc = __shfl_up(c, s, 64);
            if (lane >= s) {
                float nq = p * pc + c;
                p = pp * p;
                c = nq;
            }
        }
        if (lane == 63) { sm2[wv * 2] = p; sm2[wv * 2 + 1] = c; }
        __syncthreads();
        float wP = 1.f, wQ = 0.f;
        for (int i = 0; i < wv; ++i) {
            float gp = sm2[i * 2], gq = sm2[i * 2 + 1];
            wQ = gp * wQ + gq;
            wP = wP * gp;
        }
        {
            float nq = p * wQ + c;
            p = wP * p;
            c = nq;
        }
        if (tid == TPB - 1) {
            AT_STORE(&scrP[b], p); AT_STORE(&scrQ[b], c);
            __atomic_signal_fence(__ATOMIC_SEQ_CST);
            __builtin_amdgcn_s_waitcnt(0);
            __atomic_signal_fence(__ATOMIC_SEQ_CST);
            AT_STORE(&f2[b], MAGIC);
        }
        float eP, eQ;
        {
            float pp = __shfl_up(p, 1, 64), pc = __shfl_up(c, 1, 64);
            eP = (lane == 0) ? wP : pp;
            eQ = (lane == 0) ? wQ : pc;
        }
        if (tid == 0) {
            float accP = 1.f, Bst = 0.f;
            int j = b - 1;
            for (;;) {
                if (j < 0) { Bst += accP * 1.0f; break; }
                if (accP < 1e-35f) break;
                while (AT_LOAD(&f2[j]) != MAGIC) __builtin_amdgcn_s_sleep(1);
                __atomic_signal_fence(__ATOMIC_ACQUIRE);
                float Pj = AT_LOAD(&scrP[j]), Qj = AT_LOAD(&scrQ[j]);
                Bst  += accP * Qj;
                accP *= Pj;
                --j;
            }
            bc[1] = Bst;
        }
        __syncthreads();
        float Bst = eP * bc[1] + eQ;
        if (full) {
            float f = omk * Bst;
#pragma unroll
            for (int j = 0; j < ITEMS; ++j) { d[j] += f; f *= k; }
            fx4* o4 = (fx4*)out + ((long)(gbase + toff) >> 2);
#pragma unroll
            for (int u = 0; u < 8; ++u) {
                fx4 v; v.x = d[4 * u]; v.y = d[4 * u + 1]; v.z = d[4 * u + 2]; v.w = d[4 * u + 3];
                __builtin_nontemporal_store(v, &o4[u]);
            }
        }
    }
}

extern "C" void kernel_launch(void* const* d_in, const int* in_sizes, int n_in,
                              void* d_out, int out_size, void* d_ws, size_t ws_size,
                              hipStream_t stream) {
    const float* x    = (const float*)d_in[0];
    const float* BFI  = (const float*)d_in[1];
    const float* K    = (const float*)d_in[2];
    const float* Smax = (const float*)d_in[3];
    float* out = (float*)d_out;
    float* ws  = (float*)d_ws;   // needs ~27.4 KB; 0xAA poison = "not ready" for flags
    int T = out_size;            // 8,000,000

    awbm_kernel<<<dim3(GRID), dim3(TPB), 0, stream>>>(x, BFI, K, Smax, out, ws, T);
}

// Round 5
// 114.771 us; speedup vs baseline: 1.3082x; 1.3082x over previous
//
#include <hip/hip_runtime.h>

constexpr int TPB   = 256;
constexpr int ITEMS = 32;
constexpr int TILE  = TPB * ITEMS;   // 8192 elements per block
constexpr int GRID  = 977;           // 977*8192 = 8,003,584 >= 8,000,000
constexpr unsigned MAGIC = 0xC0DE600Du;   // != 0xAAAAAAAA ws-poison, != 0

// native 4-float vector (layout-identical to HIP float4)
typedef float fx4 __attribute__((ext_vector_type(4)));

// Clamp monoid: f(x) = min(max(x + A, B), C). compose(l, r) (l applied first):
//   A = Al + Ar;  B = max(Bl + Ar, Br);  C = min(max(Cl + Ar, Br), Cr)
// Affine monoid: f(x) = P*x + Q. compose(l, r): P = Pl*Pr; Q = Pr*Ql + Qr.
//
// R15 = R14 with ALL nontemporal accesses reverted to plain cached accesses.
// R14's rocprof (kernel 62us, WRITE_SIZE 82.6MB vs 32MB ideal, HBM 1.9TB/s)
// proved the NT flags caused 2.6x write amplification: per-thread ownership
// writes 64x16B partial lines per instruction at 128B lane stride; CACHED
// stores let L2 merge the 8 consecutive instructions into one full-line
// writeback per line, NT stores send each 16B chunk unmerged to the memory
// controller (read-modify-write). Same mechanism on loads: L1/L2 temporal
// line completion + ~27MB of L3 read hits (FETCH 36.7MB < 64MB input) make
// the strided pattern free ONLY through the caches. Never bypass caches here.
// Kept from R14 (validated, no memory interaction):
//  * k32 hoist: p == k^ITEMS for every full thread (32 dependent v_mul gone).
//  * lane-0 exact fix-up covers [0,32) only; speculative stores tid >= 1
//    (tid 1 saturated on fast path; B-start error damped by k^32 <= 1.1e-5).
// Structure otherwise identical to R10: gate-free throughput path, exact
// publishes, speculative epilogue, runtime fallback (exact R9 broadcast).
// Deadlock-freedom: waits target only lower blockIdx; ascending dispatch;
// 977 blocks at 4/CU fully co-resident.

#define AT_LOAD(p)    __hip_atomic_load((p), __ATOMIC_RELAXED, __HIP_MEMORY_SCOPE_AGENT)
#define AT_STORE(p,v) __hip_atomic_store((p), (v), __ATOMIC_RELAXED, __HIP_MEMORY_SCOPE_AGENT)

__global__ __launch_bounds__(TPB, 4)
void awbm_kernel(const float* __restrict__ x,
                 const float* __restrict__ pBFI,
                 const float* __restrict__ pK,
                 const float* __restrict__ pSmax,
                 float* __restrict__ out,
                 float* __restrict__ ws,
                 int T)
{
    __shared__ float sm3[12];    // phase-A wave aggregates (3 x 4 waves)
    __shared__ float sm2[8];     // phase-C wave aggregates (2 x 4 waves)
    __shared__ float bc[2];      // fallback broadcast: S / B at block start

    const int tid  = threadIdx.x;
    const int lane = tid & 63;
    const int wv   = tid >> 6;
    const int b    = blockIdx.x;
    const int gbase = b * TILE;
    const int toff  = tid * ITEMS;
    const bool full = (gbase + toff) < T;      // all-or-nothing (divisibility)

    // ---- stage x -> registers FIRST: 16 independent cached dwordx4 loads ----
    float d[ITEMS];
    if (full) {
        const fx4* x4 = (const fx4*)x + ((long)(gbase + toff) >> 1);
        fx4 v[16];
#pragma unroll
        for (int u = 0; u < 16; ++u) v[u] = x4[u];
#pragma unroll
        for (int u = 0; u < 16; ++u) {
            d[2 * u]     = v[u].x - v[u].y;
            d[2 * u + 1] = v[u].z - v[u].w;
        }
    }

    float*    scrA = ws;
    float*    scrB = ws + GRID;
    float*    scrC = ws + 2 * GRID;
    float*    scrP = ws + 3 * GRID;
    float*    scrQ = ws + 4 * GRID;
    unsigned* f1   = (unsigned*)(ws + 5 * GRID);
    unsigned* f2   = (unsigned*)(ws + 6 * GRID);

    const float bfi  = pBFI[0];
    const float k    = pK[0];
    const float smax = pSmax[0];
    const float omb  = 1.0f - bfi;
    const float omk  = 1.0f - k;
    const float INF  = __builtin_inff();
    const float k2 = k * k, k4 = k2 * k2, k8 = k4 * k4, k16 = k8 * k8;
    const float k32 = k16 * k16;               // per-full-thread affine P

    // ---- Phase A: per-thread clamp fold (identity if empty) ----
    float rA = 0.f, rB = -INF, rC = INF;
    if (full) {
#pragma unroll
        for (int j = 0; j < ITEMS; ++j) {
            float dd = d[j];
            rA += dd;
            rB = fmaxf(rB + dd, 0.f);
            rC = fminf(fmaxf(rC + dd, 0.f), smax);
        }
    }
#pragma unroll
    for (int s = 1; s < 64; s <<= 1) {
        float pA = __shfl_up(rA, s, 64), pB = __shfl_up(rB, s, 64), pC = __shfl_up(rC, s, 64);
        if (lane >= s) {
            float nA = pA + rA, nB = fmaxf(pB + rA, rB), nC = fminf(fmaxf(pC + rA, rB), rC);
            rA = nA; rB = nB; rC = nC;
        }
    }
    if (lane == 63) { sm3[wv * 3] = rA; sm3[wv * 3 + 1] = rB; sm3[wv * 3 + 2] = rC; }
    __syncthreads();   // B1
    float wA = 0.f, wB = -INF, wC = INF;       // exclusive cross-wave prefix
    for (int i = 0; i < wv; ++i) {
        float a = sm3[i * 3], bb = sm3[i * 3 + 1], c = sm3[i * 3 + 2];
        float nA = wA + a, nB = fmaxf(wB + a, bb), nC = fminf(fmaxf(wC + a, bb), c);
        wA = nA; wB = nB; wC = nC;
    }
    {   // thread inclusive across block
        float nA = wA + rA, nB = fmaxf(wB + rA, rB), nC = fminf(fmaxf(wC + rA, rB), rC);
        rA = nA; rB = nB; rC = nC;
    }
    if (tid == TPB - 1) {                      // publish1: exact, gate-free
        AT_STORE(&scrA[b], rA); AT_STORE(&scrB[b], rB); AT_STORE(&scrC[b], rC);
        __atomic_signal_fence(__ATOMIC_SEQ_CST);
        __builtin_amdgcn_s_waitcnt(0);
        __atomic_signal_fence(__ATOMIC_SEQ_CST);
        AT_STORE(&f1[b], MAGIC);
    }
    float eA, eB, eC;                          // thread-exclusive prefix map
    {
        float pA = __shfl_up(rA, 1, 64), pB = __shfl_up(rB, 1, 64), pC = __shfl_up(rC, 1, 64);
        eA = (lane == 0) ? wA : pA;
        eB = (lane == 0) ? wB : pB;
        eC = (lane == 0) ? wC : pC;
    }

    // ---- fast/fallback decision (B2) ----
    int bad = (full && tid > 0 && eB < eC) ? 1 : 0;
    int cnt = __syncthreads_count(bad);
    const bool fallback = (cnt != 0) || !(k > 0.0f && k < 0.70f) || (T - gbase < 64);

    if (!fallback) {
        // ================= FAST PATH (gate-free throughput) =================
        float S = fminf(fmaxf(0.5f + eA, eB), eC);   // exact for saturated threads
        float c = 0.f;
        if (full) {
#pragma unroll
            for (int j = 0; j < ITEMS; ++j) {
                float dd = d[j];
                float S1 = fmaxf(S + dd, 0.f);
                float ex = fmaxf(S1 - smax, 0.f);
                S = S1 - ex;
                float w = c + bfi * ex;
                d[j] = omb * ex + omk * w;
                c = k * w;
            }
        }
        float p = full ? k32 : 1.f;            // hoisted: P = k^ITEMS, constant
#pragma unroll
        for (int s = 1; s < 64; s <<= 1) {
            float pp = __shfl_up(p, s, 64), pc = __shfl_up(c, s, 64);
            if (lane >= s) {
                float nq = p * pc + c;
                p = pp * p;
                c = nq;
            }
        }
        if (lane == 63) { sm2[wv * 2] = p; sm2[wv * 2 + 1] = c; }
        __syncthreads();   // B3
        float wP = 1.f, wQ = 0.f;
        for (int i = 0; i < wv; ++i) {
            float gp = sm2[i * 2], gq = sm2[i * 2 + 1];
            wQ = gp * wQ + gq;
            wP = wP * gp;
        }
        {
            float nq = p * wQ + c;
            p = wP * p;
            c = nq;
        }
        if (tid == TPB - 1) {                  // publish2: exact to <1e-35, gate-free
            AT_STORE(&scrP[b], p); AT_STORE(&scrQ[b], c);
            __atomic_signal_fence(__ATOMIC_SEQ_CST);
            __builtin_amdgcn_s_waitcnt(0);
            __atomic_signal_fence(__ATOMIC_SEQ_CST);
            AT_STORE(&f2[b], MAGIC);
        }
        float eP, eQ;
        {
            float pp = __shfl_up(p, 1, 64), pc = __shfl_up(c, 1, 64);
            eP = (lane == 0) ? wP : pp;
            eQ = (lane == 0) ? wQ : pc;
        }

        // speculative epilogue + store: threads >= 1, zero waits
        // (tid 1 saturated => S exact; B-start error damped by k^32 <= 1.1e-5)
        if (full && tid >= 1) {
            float Bst = eP * 1.0f + eQ;        // guess B_blockstart=1; err <= k^(32*tid)
            float f = omk * Bst;
#pragma unroll
            for (int j = 0; j < ITEMS; ++j) { d[j] += f; f *= k; }
            fx4* o4 = (fx4*)out + ((long)(gbase + toff) >> 2);
#pragma unroll
            for (int u = 0; u < 8; ++u) {
                fx4 v; v.x = d[4 * u]; v.y = d[4 * u + 1]; v.z = d[4 * u + 2]; v.w = d[4 * u + 3];
                o4[u] = v;
            }
        }

        // lane-0 fix-up: both 1-hop gates + exact serial recompute of [0,32)
        if (tid == 0) {
            float Sst;
            if (b == 0) Sst = 0.5f;
            else {
                float aA = 0.f, aB = -INF, aC = INF;
                int j = b - 1;
                for (;;) {
                    if (j < 0) { Sst = fminf(fmaxf(0.5f + aA, aB), aC); break; }
                    while (AT_LOAD(&f1[j]) != MAGIC) __builtin_amdgcn_s_sleep(1);
                    __atomic_signal_fence(__ATOMIC_ACQUIRE);
                    float Aj = AT_LOAD(&scrA[j]), Bj = AT_LOAD(&scrB[j]), Cj = AT_LOAD(&scrC[j]);
                    float nA = Aj + aA, nB = fmaxf(Bj + aA, aB), nC = fminf(fmaxf(Cj + aA, aB), aC);
                    aA = nA; aB = nB; aC = nC;
                    if (aB >= aC) { Sst = aC; break; }
                    --j;
                }
            }
            float Bcur;
            if (b == 0) Bcur = 1.0f;
            else {
                float accP = 1.f, Bacc = 0.f;
                int j = b - 1;
                for (;;) {
                    if (j < 0) { Bacc += accP * 1.0f; break; }
                    if (accP < 1e-35f) break;
                    while (AT_LOAD(&f2[j]) != MAGIC) __builtin_amdgcn_s_sleep(1);
                    __atomic_signal_fence(__ATOMIC_ACQUIRE);
                    float Pj = AT_LOAD(&scrP[j]), Qj = AT_LOAD(&scrQ[j]);
                    Bacc += accP * Qj;
                    accP *= Pj;
                    --j;
                }
                Bcur = Bacc;
            }
            // exact recompute of elements [gbase, gbase+32)
            const fx4* xf = (const fx4*)x + ((long)gbase >> 1);
            fx4 vv[16];
#pragma unroll
            for (int u = 0; u < 16; ++u) vv[u] = xf[u];
            float Sc = Sst;
            float o[32];
#pragma unroll
            for (int j = 0; j < 32; ++j) {
                float dd = (j & 1) ? (vv[j >> 1].z - vv[j >> 1].w)
                                   : (vv[j >> 1].x - vv[j >> 1].y);
                float S1 = fmaxf(Sc + dd, 0.f);
                float ex = fmaxf(S1 - smax, 0.f);
                Sc = S1 - ex;
                Bcur += bfi * ex;
                float bf = omk * Bcur;
                Bcur -= bf;
                o[j] = omb * ex + bf;
            }
            fx4* o4 = (fx4*)out + ((long)gbase >> 2);
#pragma unroll
            for (int u = 0; u < 8; ++u) {
                fx4 v; v.x = o[4 * u]; v.y = o[4 * u + 1]; v.z = o[4 * u + 2]; v.w = o[4 * u + 3];
                o4[u] = v;
            }
        }
    } else {
        // ================= FALLBACK (exact R9 path) =================
        if (tid == 0) {
            float aA = 0.f, aB = -INF, aC = INF;
            float Sst;
            int j = b - 1;
            for (;;) {
                if (j < 0) { Sst = fminf(fmaxf(0.5f + aA, aB), aC); break; }
                while (AT_LOAD(&f1[j]) != MAGIC) __builtin_amdgcn_s_sleep(1);
                __atomic_signal_fence(__ATOMIC_ACQUIRE);
                float Aj = AT_LOAD(&scrA[j]), Bj = AT_LOAD(&scrB[j]), Cj = AT_LOAD(&scrC[j]);
                float nA = Aj + aA, nB = fmaxf(Bj + aA, aB), nC = fminf(fmaxf(Cj + aA, aB), aC);
                aA = nA; aB = nB; aC = nC;
                if (aB >= aC) { Sst = aC; break; }
                --j;
            }
            bc[0] = Sst;
        }
        __syncthreads();
        float S = fminf(fmaxf(bc[0] + eA, eB), eC);
        float c = 0.f;
        if (full) {
#pragma unroll
            for (int j = 0; j < ITEMS; ++j) {
                float dd = d[j];
                float S1 = fmaxf(S + dd, 0.f);
                float ex = fmaxf(S1 - smax, 0.f);
                S = S1 - ex;
                float w = c + bfi * ex;
                d[j] = omb * ex + omk * w;
                c = k * w;
            }
        }
        float p = full ? k32 : 1.f;
#pragma unroll
        for (int s = 1; s < 64; s <<= 1) {
            float pp = __shfl_up(p, s, 64), pc = __shfl_up(c, s, 64);
            if (lane >= s) {
                float nq = p * pc + c;
                p = pp * p;
                c = nq;
            }
        }
        if (lane == 63) { sm2[wv * 2] = p; sm2[wv * 2 + 1] = c; }
        __syncthreads();
        float wP = 1.f, wQ = 0.f;
        for (int i = 0; i < wv; ++i) {
            float gp = sm2[i * 2], gq = sm2[i * 2 + 1];
            wQ = gp * wQ + gq;
            wP = wP * gp;
        }
        {
            float nq = p * wQ + c;
            p = wP * p;
            c = nq;
        }
        if (tid == TPB - 1) {
            AT_STORE(&scrP[b], p); AT_STORE(&scrQ[b], c);
            __atomic_signal_fence(__ATOMIC_SEQ_CST);
            __builtin_amdgcn_s_waitcnt(0);
            __atomic_signal_fence(__ATOMIC_SEQ_CST);
            AT_STORE(&f2[b], MAGIC);
        }
        float eP, eQ;
        {
            float pp = __shfl_up(p, 1, 64), pc = __shfl_up(c, 1, 64);
            eP = (lane == 0) ? wP : pp;
            eQ = (lane == 0) ? wQ : pc;
        }
        if (tid == 0) {
            float accP = 1.f, Bst = 0.f;
            int j = b - 1;
            for (;;) {
                if (j < 0) { Bst += accP * 1.0f; break; }
                if (accP < 1e-35f) break;
                while (AT_LOAD(&f2[j]) != MAGIC) __builtin_amdgcn_s_sleep(1);
                __atomic_signal_fence(__ATOMIC_ACQUIRE);
                float Pj = AT_LOAD(&scrP[j]), Qj = AT_LOAD(&scrQ[j]);
                Bst  += accP * Qj;
                accP *= Pj;
                --j;
            }
            bc[1] = Bst;
        }
        __syncthreads();
        float Bst = eP * bc[1] + eQ;
        if (full) {
            float f = omk * Bst;
#pragma unroll
            for (int j = 0; j < ITEMS; ++j) { d[j] += f; f *= k; }
            fx4* o4 = (fx4*)out + ((long)(gbase + toff) >> 2);
#pragma unroll
            for (int u = 0; u < 8; ++u) {
                fx4 v; v.x = d[4 * u]; v.y = d[4 * u + 1]; v.z = d[4 * u + 2]; v.w = d[4 * u + 3];
                o4[u] = v;
            }
        }
    }
}

extern "C" void kernel_launch(void* const* d_in, const int* in_sizes, int n_in,
                              void* d_out, int out_size, void* d_ws, size_t ws_size,
                              hipStream_t stream) {
    const float* x    = (const float*)d_in[0];
    const float* BFI  = (const float*)d_in[1];
    const float* K    = (const float*)d_in[2];
    const float* Smax = (const float*)d_in[3];
    float* out = (float*)d_out;
    float* ws  = (float*)d_ws;   // needs ~27.4 KB; 0xAA poison = "not ready" for flags
    int T = out_size;            // 8,000,000

    awbm_kernel<<<dim3(GRID), dim3(TPB), 0, stream>>>(x, BFI, K, Smax, out, ws, T);
}